// Round 2
// baseline (103.666 us; speedup 1.0000x reference)
//
#include <hip/hip_runtime.h>
#include <hip/hip_bf16.h>
#include <math.h>

// Problem constants (match reference setup_inputs)
#define BB 2048
#define CC 1000
#define PP 20
#define C4 (CC / 4)   // 250 float4 per row; rows are 4000B -> always 16B aligned

// Zero the 2-word atomic scratch (d_ws is poisoned 0xAA before every call).
__global__ __launch_bounds__(64) void lesp_init_kernel(unsigned* __restrict__ cnt,
                                                       float* __restrict__ acc)
{
    if (threadIdx.x == 0) { *cnt = 0u; *acc = 0.0f; }
}

// One block per row, fused finalize:
//   S_b   = sum_j exp(-x[b,j])
//   P_b   = sum_{valid p} ( exp(x[b,t_{b,p}]) * S_b - 1 )
//   loss  = log1p( sum_b P_b ) / C     (written by the last block to finish)
// Identity: sum_{j != t} exp(x_t - x_j) = exp(x_t)*S_b - 1.
__global__ __launch_bounds__(256) void lesp_fused_kernel(
    const float* __restrict__ x,
    const int* __restrict__ tgt,
    float* __restrict__ out,
    float* __restrict__ acc,
    unsigned* __restrict__ cnt)
{
    __shared__ float4 lds4[C4];
    __shared__ float wave_sums[4];

    const int b   = blockIdx.x;
    const int tid = threadIdx.x;
    const float4* row4 = (const float4*)(x + (size_t)b * CC);

    // One float4 per thread (threads 0..249): stage to LDS + accumulate exp(-x)
    float s = 0.0f;
    if (tid < C4) {
        float4 v = row4[tid];
        lds4[tid] = v;                       // single ds_write_b128, conflict-free
        s = __expf(-v.x) + __expf(-v.y) + __expf(-v.z) + __expf(-v.w);
    }

    // 64-lane wave shuffle reduction
    for (int off = 32; off > 0; off >>= 1)
        s += __shfl_down(s, off, 64);
    if ((tid & 63) == 0) wave_sums[tid >> 6] = s;
    __syncthreads();   // fences both lds4 and wave_sums

    // Lanes 0..19 (wave 0) handle the P targets
    float term = 0.0f;
    if (tid < PP) {
        const float S = wave_sums[0] + wave_sums[1] + wave_sums[2] + wave_sums[3];
        int t = tgt[b * PP + tid];
        if (t > -1) {
            float xt = ((const float*)lds4)[t];
            term = __expf(xt) * S - 1.0f;
        }
    }
    for (int off = 32; off > 0; off >>= 1)
        term += __shfl_down(term, off, 64);

    // Block leader: accumulate + ticket; last block finalizes.
    if (tid == 0) {
        atomicAdd(acc, term);               // device-scope by default on CDNA
        __threadfence();
        unsigned old = atomicAdd(cnt, 1u);
        if (old == (unsigned)(gridDim.x - 1)) {
            __threadfence();
            float total = atomicAdd(acc, 0.0f);   // coherent read of final sum
            out[0] = log1pf(total) * (1.0f / (float)CC);
        }
    }
}

extern "C" void kernel_launch(void* const* d_in, const int* in_sizes, int n_in,
                              void* d_out, int out_size, void* d_ws, size_t ws_size,
                              hipStream_t stream)
{
    const float* x   = (const float*)d_in[0];   // [B, C] fp32
    const int*   tgt = (const int*)d_in[1];     // [B, P] int
    float* out       = (float*)d_out;           // [1] fp32

    unsigned* cnt = (unsigned*)d_ws;            // ticket counter
    float*    acc = (float*)((char*)d_ws + 64); // fp32 accumulator (own cacheline)

    lesp_init_kernel<<<1, 64, 0, stream>>>(cnt, acc);
    lesp_fused_kernel<<<BB, 256, 0, stream>>>(x, tgt, out, acc, cnt);
}

// Round 3
// 63.474 us; speedup vs baseline: 1.6332x; 1.6332x over previous
//
#include <hip/hip_runtime.h>
#include <hip/hip_bf16.h>
#include <math.h>

// Problem constants (match reference setup_inputs)
#define BB 2048
#define CC 1000
#define PP 20
#define C4 (CC / 4)   // 250 float4 per row; rows are 4000B -> 16B aligned

// Kernel A: one 64-lane wave per row. No LDS, no barriers.
//   S_b = sum_j exp(-x[b,j])
//   E_b = sum_{valid p} exp(x[b,t_{b,p}]),  n_b = #valid
//   partial[b] = E_b * S_b - n_b
// Identity: sum_{valid p} sum_{j != t_p} exp(x_t - x_j) = E_b*S_b - n_b.
__global__ __launch_bounds__(64) void lesp_row_kernel(
    const float* __restrict__ x,
    const int* __restrict__ tgt,
    float* __restrict__ partial)
{
    const int b    = blockIdx.x;
    const int lane = threadIdx.x;           // 0..63
    const float4* row4 = (const float4*)(x + (size_t)b * CC);

    // Row pass: up to 4 float4 per lane (250 = 3*64 + 58)
    float s = 0.0f;
#pragma unroll
    for (int k = 0; k < 4; ++k) {
        int idx = lane + 64 * k;
        if (idx < C4) {
            float4 v = row4[idx];
            s += __expf(-v.x) + __expf(-v.y) + __expf(-v.z) + __expf(-v.w);
        }
    }

    // Target gather (lanes 0..19), straight from global (L1/L2-hot)
    float e = 0.0f, n = 0.0f;
    if (lane < PP) {
        int t = tgt[b * PP + lane];
        if (t > -1) {
            e = __expf(x[(size_t)b * CC + t]);
            n = 1.0f;
        }
    }

    // Combined wave shuffle reduction of (s, e, n)
    for (int off = 32; off > 0; off >>= 1) {
        s += __shfl_down(s, off, 64);
        e += __shfl_down(e, off, 64);
        n += __shfl_down(n, off, 64);
    }

    if (lane == 0) partial[b] = e * s - n;
}

// Kernel B: reduce 2048 partials, finalize. Kernel boundary provides the
// release/acquire — no fences/atomics anywhere.
__global__ __launch_bounds__(256) void lesp_finalize_kernel(
    const float* __restrict__ partial,
    float* __restrict__ out)
{
    __shared__ float wave_sums[4];

    float s = 0.0f;
    for (int i = threadIdx.x; i < BB; i += 256)
        s += partial[i];

    for (int off = 32; off > 0; off >>= 1)
        s += __shfl_down(s, off, 64);

    if ((threadIdx.x & 63) == 0) wave_sums[threadIdx.x >> 6] = s;
    __syncthreads();

    if (threadIdx.x == 0) {
        float total = wave_sums[0] + wave_sums[1] + wave_sums[2] + wave_sums[3];
        out[0] = log1pf(total) * (1.0f / (float)CC);
    }
}

extern "C" void kernel_launch(void* const* d_in, const int* in_sizes, int n_in,
                              void* d_out, int out_size, void* d_ws, size_t ws_size,
                              hipStream_t stream)
{
    const float* x   = (const float*)d_in[0];   // [B, C] fp32
    const int*   tgt = (const int*)d_in[1];     // [B, P] int
    float* out       = (float*)d_out;           // [1] fp32
    float* partial   = (float*)d_ws;            // BB floats (all written in kernel A)

    lesp_row_kernel<<<BB, 64, 0, stream>>>(x, tgt, partial);
    lesp_finalize_kernel<<<1, 256, 0, stream>>>(partial, out);
}

// Round 4
// 62.383 us; speedup vs baseline: 1.6617x; 1.0175x over previous
//
#include <hip/hip_runtime.h>
#include <hip/hip_bf16.h>
#include <math.h>

// Problem constants (match reference setup_inputs)
#define BB 2048
#define CC 1000
#define PP 20
#define C4 (CC / 4)        // 250 float4 per row; rows are 4000B -> 16B aligned
#define NBLK 256           // 1 block per CU
#define WAVES_PER_BLK 4
#define TOTAL_WAVES (NBLK * WAVES_PER_BLK)   // 1024; each wave does 2 rows

#define POISON_U 0xAAAAAAAAu

// Single fused kernel, fence-free finalize.
// Per row b:  S_b = sum_j exp(-x[b,j]);  E_b = sum_{valid p} exp(x[b,t_p]);
//             partial_b = E_b*S_b - n_b   (identity: sum_{j!=t} exp(x_t-x_j))
// Block partial accumulated -> one returning atomicAdd(acc) -> data-dependent
// atomicAdd(cnt) ticket -> last block RMW-reads acc and writes the loss.
// No __threadfence: all cross-block communication is via device-scope atomic
// RMWs to two words, serialized at the coherent point; the data dependency
// (acc result feeds the ticket operand) orders acc-add before cnt-add.
__global__ __launch_bounds__(256) void lesp_fused_kernel(
    const float* __restrict__ x,
    const int* __restrict__ tgt,
    float* __restrict__ out,
    float* __restrict__ acc,
    unsigned* __restrict__ cnt)
{
    __shared__ float wave_sums[WAVES_PER_BLK];

    const int tid  = threadIdx.x;
    const int lane = tid & 63;
    const int wave = tid >> 6;
    const int wgid = blockIdx.x * WAVES_PER_BLK + wave;   // 0..1023

    float p = 0.0f;   // lane-0 accumulates per-row partials here

#pragma unroll
    for (int rr = 0; rr < 2; ++rr) {
        const int b = wgid + rr * TOTAL_WAVES;            // rows wgid, wgid+1024
        const float4* row4 = (const float4*)(x + (size_t)b * CC);

        float s = 0.0f;
#pragma unroll
        for (int k = 0; k < 4; ++k) {
            int idx = lane + 64 * k;
            if (idx < C4) {
                float4 v = row4[idx];
                s += __expf(-v.x) + __expf(-v.y) + __expf(-v.z) + __expf(-v.w);
            }
        }

        float e = 0.0f, n = 0.0f;
        if (lane < PP) {
            int t = tgt[b * PP + lane];
            if (t > -1) {
                e = __expf(x[(size_t)b * CC + t]);
                n = 1.0f;
            }
        }

        for (int off = 32; off > 0; off >>= 1) {
            s += __shfl_down(s, off, 64);
            e += __shfl_down(e, off, 64);
            n += __shfl_down(n, off, 64);
        }
        if (lane == 0) p += e * s - n;
    }

    if (lane == 0) wave_sums[wave] = p;
    __syncthreads();

    if (tid == 0) {
        float blk = wave_sums[0] + wave_sums[1] + wave_sums[2] + wave_sums[3];

        // Returning atomic: completes at the coherent point before `dep` exists.
        float r = atomicAdd(acc, blk);
        unsigned dep = __float_as_uint(r) & 0u;           // always 0, forces order
        unsigned old = atomicAdd(cnt, 1u | dep);

        // Accept both documented ws initial states: 0xAA poison or zeros.
        bool last_poison = (old == POISON_U + (NBLK - 1u));
        bool last_zero   = (old == (unsigned)(NBLK - 1));
        if (last_poison || last_zero) {
            float total = atomicAdd(acc, 0.0f);           // coherent RMW read
            if (last_poison) total -= __uint_as_float(POISON_U);
            out[0] = log1pf(total) * (1.0f / (float)CC);
        }
    }
}

extern "C" void kernel_launch(void* const* d_in, const int* in_sizes, int n_in,
                              void* d_out, int out_size, void* d_ws, size_t ws_size,
                              hipStream_t stream)
{
    const float* x   = (const float*)d_in[0];   // [B, C] fp32
    const int*   tgt = (const int*)d_in[1];     // [B, P] int
    float* out       = (float*)d_out;           // [1] fp32

    unsigned* cnt = (unsigned*)d_ws;                 // ticket (poisoned start OK)
    float*    acc = (float*)((char*)d_ws + 128);     // accumulator, own cacheline

    lesp_fused_kernel<<<NBLK, 256, 0, stream>>>(x, tgt, out, acc, cnt);
}

// Round 5
// 62.199 us; speedup vs baseline: 1.6667x; 1.0030x over previous
//
#include <hip/hip_runtime.h>
#include <hip/hip_bf16.h>
#include <math.h>

// Problem constants (match reference setup_inputs)
#define BB 2048
#define CC 1000
#define PP 20
#define C4 (CC / 4)        // 250 float4 per row; rows are 4000B -> 16B aligned
#define NBLK 256           // 1 block per CU; 256 atomic leaders
#define TPB 512            // 8 waves/block -> 2048 waves total = 1 row per wave
#define WAVES_PER_BLK (TPB / 64)

#define POISON_U 0xAAAAAAAAu

// Single fused kernel, fence-free finalize. One 64-lane wave per row.
//   S_b = sum_j exp(-x[b,j]);  E_b = sum_{valid p} exp(x[b,t_p]);  n_b = #valid
//   partial_b = E_b*S_b - n_b     (identity: sum_{j!=t} exp(x_t - x_j))
// All cross-block communication is via device-scope atomic RMWs (coherent
// point); the returning acc-add feeds a data dependency into the ticket add,
// so no __threadfence is needed (R2 showed per-block fences cost ~45 us here).
__global__ __launch_bounds__(TPB) void lesp_fused_kernel(
    const float* __restrict__ x,
    const int* __restrict__ tgt,
    float* __restrict__ out,
    float* __restrict__ acc,
    unsigned* __restrict__ cnt)
{
    __shared__ float wave_sums[WAVES_PER_BLK];

    const int tid  = threadIdx.x;
    const int lane = tid & 63;
    const int wave = tid >> 6;
    const int b    = blockIdx.x * WAVES_PER_BLK + wave;   // row, 0..2047

    const float4* row4 = (const float4*)(x + (size_t)b * CC);

    // Row pass: lanes 0..57 read 4 float4, lanes 58..63 read 3 (250 total)
    float s = 0.0f;
#pragma unroll
    for (int k = 0; k < 4; ++k) {
        int idx = lane + 64 * k;
        if (idx < C4) {
            float4 v = row4[idx];
            s += __expf(-v.x) + __expf(-v.y) + __expf(-v.z) + __expf(-v.w);
        }
    }

    // Target gather (lanes 0..19), straight from global (row is L1-hot)
    float e = 0.0f, n = 0.0f;
    if (lane < PP) {
        int t = tgt[b * PP + lane];
        if (t > -1) {
            e = __expf(x[(size_t)b * CC + t]);
            n = 1.0f;
        }
    }

    // Combined wave shuffle reduction of (s, e, n)
    for (int off = 32; off > 0; off >>= 1) {
        s += __shfl_down(s, off, 64);
        e += __shfl_down(e, off, 64);
        n += __shfl_down(n, off, 64);
    }
    if (lane == 0) wave_sums[wave] = e * s - n;
    __syncthreads();

    if (tid == 0) {
        float blk = 0.0f;
#pragma unroll
        for (int w = 0; w < WAVES_PER_BLK; ++w) blk += wave_sums[w];

        // Returning atomic completes at the coherent point before `dep` exists.
        float r = atomicAdd(acc, blk);
        unsigned dep = __float_as_uint(r) & 0u;           // always 0, forces order
        unsigned old = atomicAdd(cnt, 1u | dep);

        // Accept both documented ws initial states: 0xAA poison or zeros.
        bool last_poison = (old == POISON_U + (NBLK - 1u));
        bool last_zero   = (old == (unsigned)(NBLK - 1));
        if (last_poison || last_zero) {
            float total = atomicAdd(acc, 0.0f);           // coherent RMW read
            if (last_poison) total -= __uint_as_float(POISON_U);
            out[0] = log1pf(total) * (1.0f / (float)CC);
        }
    }
}

extern "C" void kernel_launch(void* const* d_in, const int* in_sizes, int n_in,
                              void* d_out, int out_size, void* d_ws, size_t ws_size,
                              hipStream_t stream)
{
    const float* x   = (const float*)d_in[0];   // [B, C] fp32
    const int*   tgt = (const int*)d_in[1];     // [B, P] int
    float* out       = (float*)d_out;           // [1] fp32

    unsigned* cnt = (unsigned*)d_ws;                 // ticket (poisoned start OK)
    float*    acc = (float*)((char*)d_ws + 128);     // accumulator, own cacheline

    lesp_fused_kernel<<<NBLK, TPB, 0, stream>>>(x, tgt, out, acc, cnt);
}